// Round 1
// baseline (1422.348 us; speedup 1.0000x reference)
//
#include <hip/hip_runtime.h>
#include <stdint.h>

static constexpr int MM   = 2000;   // sites
static constexpr int NN   = 1000;   // states
static constexpr int NB2  = 32;     // 2B haplotype rows
static constexpr int DDIM = 5000;   // gexp dim
static constexpr int NP   = 1024;   // padded states per row
static constexpr int NG   = 500;    // MM/4 groups
static constexpr float EAV = 0.991f; // (1-0.01) + 1/1000
static constexpr float EBV = 0.011f; // 0.01 + 1/1000

__device__ __forceinline__ float rcp_fast(float x){ return __builtin_amdgcn_rcpf(x); }

__device__ __forceinline__ float wave_allsum(float v){
  v += __shfl_xor(v, 1, 64);
  v += __shfl_xor(v, 2, 64);
  v += __shfl_xor(v, 4, 64);
  v += __shfl_xor(v, 8, 64);
  v += __shfl_xor(v, 16, 64);
  v += __shfl_xor(v, 32, 64);
  return v;
}

__device__ __forceinline__ float tree16(const float* w){
  float a = ((w[0]+w[1]) + (w[2]+w[3])) + ((w[4]+w[5]) + (w[6]+w[7]));
  float b = ((w[8]+w[9]) + (w[10]+w[11])) + ((w[12]+w[13]) + (w[14]+w[15]));
  return a + b;
}

__device__ __forceinline__ uint32_t bf16pk(float a, float b){
  uint32_t ua = __float_as_uint(a); ua = (ua + 0x7FFFu + ((ua>>16)&1u)) >> 16;
  uint32_t ub = __float_as_uint(b); ub = (ub + 0x7FFFu + ((ub>>16)&1u)) >> 16;
  return ua | (ub << 16);
}

__device__ __forceinline__ void store_bf16x16(uint16_t* dst, const float* u){
  uint4 s0, s1;
  s0.x = bf16pk(u[0],u[1]);   s0.y = bf16pk(u[2],u[3]);
  s0.z = bf16pk(u[4],u[5]);   s0.w = bf16pk(u[6],u[7]);
  s1.x = bf16pk(u[8],u[9]);   s1.y = bf16pk(u[10],u[11]);
  s1.z = bf16pk(u[12],u[13]); s1.w = bf16pk(u[14],u[15]);
  uint4* p = (uint4*)dst;
  p[0] = s0; p[1] = s1;
}

// ---------------- K0: pack ref bits (per-lane 16-bit masks, 4 cols/uint64) + obs bits -----
__global__ __launch_bounds__(64) void k_pack(const int* __restrict__ ref,
                                             const float* __restrict__ xoh,
                                             uint64_t* __restrict__ pack,
                                             uint32_t* __restrict__ obsw){
  int blk = blockIdx.x;
  int t = threadIdx.x;   // lane
  if (blk < NG){
    int g = blk;
    uint64_t wv = 0;
    for (int c = 0; c < 4; ++c){
      int i = g*4 + c;
      int kbase = t*16;
      uint32_t m16 = 0;
      #pragma unroll
      for (int j = 0; j < 16; ++j){
        int v = (kbase + j < NN) ? ref[(size_t)i*NN + kbase + j] : 0;
        m16 |= (uint32_t)(v & 1) << j;
      }
      wv |= (uint64_t)m16 << (16*c);
    }
    pack[(size_t)g*64 + t] = wv;
  } else {
    // obs bit packing: thread t -> b2 = t>>1, half = t&1
    int b2 = t >> 1;
    int half = t & 1;
    for (int w = half*32; w < half*32 + 32; ++w){
      uint32_t word = 0;
      for (int z = 0; z < 32; ++z){
        int i = w*32 + z;
        if (i < MM){
          float x1 = xoh[(size_t)b2*MM*2 + (size_t)i*2 + 1];
          if (x1 > 0.5f) word |= 1u << z;
        }
      }
      obsw[b2*64 + w] = word;
    }
  }
}

// ---------------- K1: GEMM partial: part[c][bb][i] = sum_{dd in chunk c} gexp[bb][dd]*W[dd][i]
__global__ __launch_bounds__(256) void k_gemm(const float* __restrict__ gexp,
                                              const float* __restrict__ W,
                                              float* __restrict__ part){
  int cb = blockIdx.x;        // 0..7 column block
  int c  = blockIdx.y;        // 0..15 d-chunk
  int t  = threadIdx.x;
  int d0 = (c*DDIM) >> 4, d1 = ((c+1)*DDIM) >> 4;
  int len = d1 - d0;          // 312 or 313
  __shared__ float lg[313*20];  // lg[dd*20 + bb], padded stride for banks+alignment
  for (int bb = 0; bb < 16; ++bb)
    for (int dd = t; dd < len; dd += 256)
      lg[dd*20 + bb] = gexp[(size_t)bb*DDIM + d0 + dd];
  __syncthreads();
  int i = cb*256 + t;
  if (i < MM){
    float acc[16];
    #pragma unroll
    for (int bb = 0; bb < 16; ++bb) acc[bb] = 0.f;
    for (int dd = 0; dd < len; ++dd){
      float w = W[(size_t)(d0 + dd)*MM + i];
      const float4* lp = (const float4*)&lg[dd*20];
      float4 g0 = lp[0], g1 = lp[1], g2 = lp[2], g3 = lp[3];
      acc[0]  += g0.x*w; acc[1]  += g0.y*w; acc[2]  += g0.z*w; acc[3]  += g0.w*w;
      acc[4]  += g1.x*w; acc[5]  += g1.y*w; acc[6]  += g1.z*w; acc[7]  += g1.w*w;
      acc[8]  += g2.x*w; acc[9]  += g2.y*w; acc[10] += g2.z*w; acc[11] += g2.w*w;
      acc[12] += g3.x*w; acc[13] += g3.y*w; acc[14] += g3.z*w; acc[15] += g3.w*w;
    }
    #pragma unroll
    for (int bb = 0; bb < 16; ++bb)
      part[((size_t)c*16 + bb)*MM + i] = acc[bb];
  }
}

// ---------------- K2: reduce GEMM partials -> raw logits acc[bb][i] (pre-bias, pre-sigmoid)
__global__ __launch_bounds__(256) void k_gemmreduce(const float* __restrict__ part,
                                                    float* __restrict__ acc){
  int idx = blockIdx.x*256 + threadIdx.x;
  if (idx < 16*MM){
    float s = 0.f;
    #pragma unroll
    for (int c = 0; c < 16; ++c) s += part[(size_t)c*16*MM + idx];
    acc[idx] = s;
  }
}

// ---------------- K3: the two sequential chains. blocks 0..31: forward (stores F),
//                      blocks 32..63: backward state chain (stores S). One wave each.
__global__ __launch_bounds__(64) void k_chains(const float* __restrict__ recomb,
                                               const uint64_t* __restrict__ pack,
                                               const uint32_t* __restrict__ obsw,
                                               const float* __restrict__ acc,
                                               const float* __restrict__ bias,
                                               uint16_t* __restrict__ F,
                                               uint16_t* __restrict__ S){
  int lane = threadIdx.x;
  int blk  = blockIdx.x;
  bool isF = blk < 32;
  int b2   = blk & 31;
  int kb   = lane*16;

  float u[16];
  #pragma unroll
  for (int j = 0; j < 16; ++j) u[j] = (kb + j < NN) ? 1.0f : 0.0f;

  if (isF){
    // ---------------- forward ----------------
    uint64_t pk = pack[(size_t)0*64 + lane];
    float r0[4];
    #pragma unroll
    for (int c = 0; c < 4; ++c){ int i = c; r0[c] = (i+1 < MM) ? recomb[i+1] : 0.5f; }
    uint32_t ow = obsw[b2*64 + 0];

    for (int g = 0; g < NG; ++g){
      uint64_t pknext = 0; uint32_t ownext = 0;
      float rn[4] = {0.f,0.f,0.f,0.f};
      if (g+1 < NG){
        pknext = pack[(size_t)(g+1)*64 + lane];
        #pragma unroll
        for (int c = 0; c < 4; ++c){ int i = (g+1)*4 + c; rn[c] = (i+1 < MM) ? recomb[i+1] : 0.5f; }
        ownext = obsw[b2*64 + ((g+1) >> 3)];
      }
      #pragma unroll
      for (int c = 0; c < 4; ++c){
        int i = g*4 + c;
        // store F_i = u (state BEFORE applying site i)
        store_bf16x16(F + ((size_t)i*NB2 + b2)*NP + kb, u);
        uint32_t obsb = (ow >> (i & 31)) & 1u;
        uint32_t m16  = (uint32_t)(pk >> (16*c)) & 0xFFFFu;
        uint32_t em   = obsb ? (~m16 & 0xFFFFu) : m16;   // bit=1 -> match -> ea
        float w[16];
        #pragma unroll
        for (int j = 0; j < 16; ++j){
          float e = ((em >> j) & 1u) ? EAV : EBV;
          w[j] = u[j]*e;
        }
        float Z = wave_allsum(tree16(w));
        float r = r0[c];
        float sc = (1.0f - r) * rcp_fast(Z);
        float ad = r * (1.0f/(float)NN);
        #pragma unroll
        for (int j = 0; j < 16; ++j) u[j] = (kb + j < NN) ? (w[j]*sc + ad) : 0.0f;
      }
      pk = pknext; ow = ownext;
      r0[0]=rn[0]; r0[1]=rn[1]; r0[2]=rn[2]; r0[3]=rn[3];
    }
  } else {
    // ---------------- backward state chain ----------------
    const float* accrow = acc + (size_t)(b2 >> 1)*MM;
    uint64_t pk = pack[(size_t)(NG-1)*64 + lane];
    float r0[4], p0[4];
    #pragma unroll
    for (int c = 0; c < 4; ++c){
      int i = (NG-1)*4 + c;
      r0[c] = recomb[i];
      p0[c] = rcp_fast(1.0f + __expf(-(accrow[i] + bias[i])));
    }
    for (int g = NG-1; g >= 0; --g){
      uint64_t pknext = 0;
      float rn[4] = {0.f,0.f,0.f,0.f}, pn[4] = {0.f,0.f,0.f,0.f};
      if (g > 0){
        pknext = pack[(size_t)(g-1)*64 + lane];
        #pragma unroll
        for (int c = 0; c < 4; ++c){
          int i = (g-1)*4 + c;
          rn[c] = recomb[i];
          pn[c] = rcp_fast(1.0f + __expf(-(accrow[i] + bias[i])));
        }
      }
      #pragma unroll
      for (int cc = 0; cc < 4; ++cc){
        int c = 3 - cc;
        int i = g*4 + c;
        // store S_i = u (backward state BEFORE applying site i)
        store_bf16x16(S + ((size_t)i*NB2 + b2)*NP + kb, u);
        uint32_t m16 = (uint32_t)(pk >> (16*c)) & 0xFFFFu;
        float p  = p0[c];
        float v0 = EAV + (EBV - EAV)*p;   // ref bit 0: ea*(1-p)+eb*p
        float v1 = EBV + (EAV - EBV)*p;   // ref bit 1: eb*(1-p)+ea*p
        float w[16];
        #pragma unroll
        for (int j = 0; j < 16; ++j){
          float e = ((m16 >> j) & 1u) ? v1 : v0;
          w[j] = u[j]*e;
        }
        float sig = wave_allsum(tree16(w));
        float r = r0[c];
        float sc = (1.0f - r) * rcp_fast(sig);
        float ad = r * (1.0f/(float)NN);
        #pragma unroll
        for (int j = 0; j < 16; ++j) u[j] = (kb + j < NN) ? (w[j]*sc + ad) : 0.0f;
      }
      pk = pknext;
      r0[0]=rn[0]; r0[1]=rn[1]; r0[2]=rn[2]; r0[3]=rn[3];
      p0[0]=pn[0]; p0[1]=pn[1]; p0[2]=pn[2]; p0[3]=pn[3];
    }
  }
}

// ---------------- K4: per-site p_xe terms (fully parallel). wave per (i,b2). ----------
__global__ __launch_bounds__(256) void k_sites(const uint16_t* __restrict__ F,
                                               const uint16_t* __restrict__ S,
                                               const uint64_t* __restrict__ pack,
                                               const uint32_t* __restrict__ obsw,
                                               const float* __restrict__ acc,
                                               const float* __restrict__ bias,
                                               float* __restrict__ terms){
  int lane = threadIdx.x & 63;
  int wid  = threadIdx.x >> 6;
  int s    = blockIdx.x*4 + wid;     // 0 .. 63999
  int i    = s >> 5;
  int b2   = s & 31;
  size_t off = ((size_t)i*NB2 + b2)*NP + lane*16;
  const uint4* fp = (const uint4*)(F + off);
  const uint4* sp = (const uint4*)(S + off);
  uint4 f0 = fp[0], f1 = fp[1];
  uint4 s0 = sp[0], s1 = sp[1];
  uint32_t m16 = (uint32_t)(pack[(size_t)(i>>2)*64 + lane] >> (16*(i&3))) & 0xFFFFu;

  uint32_t fa[8] = {f0.x,f0.y,f0.z,f0.w,f1.x,f1.y,f1.z,f1.w};
  uint32_t sa[8] = {s0.x,s0.y,s0.z,s0.w,s1.x,s1.y,s1.z,s1.w};
  float Tt = 0.f, Tb = 0.f;
  #pragma unroll
  for (int q = 0; q < 8; ++q){
    float flo = __uint_as_float(fa[q] << 16);
    float fhi = __uint_as_float(fa[q] & 0xFFFF0000u);
    float slo = __uint_as_float(sa[q] << 16);
    float shi = __uint_as_float(sa[q] & 0xFFFF0000u);
    float pl = flo*slo, ph = fhi*shi;
    Tt += pl + ph;
    Tb += (((m16 >> (2*q)) & 1u) ? pl : 0.f) + (((m16 >> (2*q+1)) & 1u) ? ph : 0.f);
  }
  Tt = wave_allsum(Tt);
  Tb = wave_allsum(Tb);
  if (lane == 0){
    uint32_t obsb = (obsw[b2*64 + (i>>5)] >> (i & 31)) & 1u;
    float z = acc[(size_t)(b2 >> 1)*MM + i] + bias[i];
    float p = rcp_fast(1.0f + __expf(-z));
    float A = Tt - Tb, B = Tb;
    float d0 = EAV*A + EBV*B;
    float d1 = EBV*A + EAV*B;
    float w0 = d0*(1.0f - p), w1 = d1*p;
    float term = __logf((obsb ? w1 : w0) * rcp_fast(w0 + w1));
    terms[s] = term;
  }
}

// ---------------- K5: final reduction of 64000 terms -> out = -sum ----------
__global__ __launch_bounds__(256) void k_final(const float* __restrict__ terms,
                                               float* __restrict__ out){
  __shared__ float red[256];
  float s = 0.f;
  for (int idx = threadIdx.x; idx < MM*NB2; idx += 256) s += terms[idx];
  red[threadIdx.x] = s;
  __syncthreads();
  for (int st = 128; st > 0; st >>= 1){
    if (threadIdx.x < st) red[threadIdx.x] += red[threadIdx.x + st];
    __syncthreads();
  }
  if (threadIdx.x == 0) out[0] = -red[0];
}

extern "C" void kernel_launch(void* const* d_in, const int* in_sizes, int n_in,
                              void* d_out, int out_size, void* d_ws, size_t ws_size,
                              hipStream_t stream){
  const float* gexp   = (const float*)d_in[0];   // [16,5000]
  const float* xoh    = (const float*)d_in[1];   // [32,2000,2]
  const float* W      = (const float*)d_in[2];   // [5000,2000]
  const float* bias   = (const float*)d_in[3];   // [2000]
  const int*   ref    = (const int*)d_in[4];     // [2000,1000]
  const float* recomb = (const float*)d_in[5];   // [2000]
  float* out = (float*)d_out;
  char* ws = (char*)d_ws;

  const size_t stateBytes = (size_t)MM*NB2*NP*2;       // 131,072,000 per array (bf16)
  size_t offF    = 0;
  size_t offS    = offF + stateBytes;
  size_t offPack = offS + stateBytes;                  // NG*64*8 = 256,000
  size_t offObs  = offPack + (size_t)NG*64*8;          // 32*64*4 = 8,192
  size_t offPart = offObs + 32*64*4;                   // 16*16*2000*4 = 2,048,000
  size_t offAcc  = offPart + (size_t)16*16*MM*4;       // 16*2000*4 = 128,000
  size_t offTerm = offAcc + (size_t)16*MM*4;           // 64000*4 = 256,000

  uint16_t* Fb   = (uint16_t*)(ws + offF);
  uint16_t* Sb   = (uint16_t*)(ws + offS);
  uint64_t* pack = (uint64_t*)(ws + offPack);
  uint32_t* obsw = (uint32_t*)(ws + offObs);
  float*    part = (float*)(ws + offPart);
  float*    accp = (float*)(ws + offAcc);
  float*    term = (float*)(ws + offTerm);

  hipLaunchKernelGGL(k_pack, dim3(NG+1), dim3(64), 0, stream, ref, xoh, pack, obsw);
  hipLaunchKernelGGL(k_gemm, dim3(8,16), dim3(256), 0, stream, gexp, W, part);
  hipLaunchKernelGGL(k_gemmreduce, dim3(125), dim3(256), 0, stream, part, accp);
  hipLaunchKernelGGL(k_chains, dim3(64), dim3(64), 0, stream, recomb, pack, obsw, accp, bias, Fb, Sb);
  hipLaunchKernelGGL(k_sites, dim3(MM*NB2/4), dim3(256), 0, stream, Fb, Sb, pack, obsw, accp, bias, term);
  hipLaunchKernelGGL(k_final, dim3(1), dim3(256), 0, stream, term, out);
}

// Round 3
// 1117.290 us; speedup vs baseline: 1.2730x; 1.2730x over previous
//
#include <hip/hip_runtime.h>
#include <stdint.h>

static constexpr int MM   = 2000;   // sites
static constexpr int NN   = 1000;   // states
static constexpr int NB2  = 32;     // 2B haplotype rows
static constexpr int DDIM = 5000;   // gexp dim
static constexpr int NPR  = 1008;   // F/S row stride in elements (63 lanes x 16)
static constexpr int NG   = 500;    // MM/4 groups
static constexpr float EAV = 0.991f; // (1-0.01) + 1/1000
static constexpr float EBV = 0.011f; // 0.01 + 1/1000

__device__ __forceinline__ float rcp_fast(float x){ return __builtin_amdgcn_rcpf(x); }

__device__ __forceinline__ float wave_allsum(float v){
  v += __shfl_xor(v, 1, 64);
  v += __shfl_xor(v, 2, 64);
  v += __shfl_xor(v, 4, 64);
  v += __shfl_xor(v, 8, 64);
  v += __shfl_xor(v, 16, 64);
  v += __shfl_xor(v, 32, 64);
  return v;
}

__device__ __forceinline__ float tree16(const float* w){
  float a = ((w[0]+w[1]) + (w[2]+w[3])) + ((w[4]+w[5]) + (w[6]+w[7]));
  float b = ((w[8]+w[9]) + (w[10]+w[11])) + ((w[12]+w[13]) + (w[14]+w[15]));
  return a + b;
}

// Full-wave sum via DPP; result read from lane 63 into an SGPR.
__device__ __forceinline__ float wave_total_sgpr(float v){
  int x;
  x = __builtin_amdgcn_update_dpp(0, __float_as_int(v), 0x111, 0xf, 0xf, true);  v += __int_as_float(x); // row_shr:1
  x = __builtin_amdgcn_update_dpp(0, __float_as_int(v), 0x112, 0xf, 0xf, true);  v += __int_as_float(x); // row_shr:2
  x = __builtin_amdgcn_update_dpp(0, __float_as_int(v), 0x114, 0xf, 0xf, true);  v += __int_as_float(x); // row_shr:4
  x = __builtin_amdgcn_update_dpp(0, __float_as_int(v), 0x118, 0xf, 0xf, true);  v += __int_as_float(x); // row_shr:8
  x = __builtin_amdgcn_update_dpp(0, __float_as_int(v), 0x142, 0xa, 0xf, false); v += __int_as_float(x); // row_bcast:15
  x = __builtin_amdgcn_update_dpp(0, __float_as_int(v), 0x143, 0xc, 0xf, false); v += __int_as_float(x); // row_bcast:31
  return __int_as_float(__builtin_amdgcn_readlane(__float_as_int(v), 63));
}

// ---------------- K0: pack ref bits + ref bytes + obs bits -----
__global__ __launch_bounds__(64) void k_pack(const int* __restrict__ ref,
                                             const float* __restrict__ xoh,
                                             uint64_t* __restrict__ pack,
                                             uint4* __restrict__ refB4,
                                             uint32_t* __restrict__ obsw){
  int blk = blockIdx.x;
  int t = threadIdx.x;   // lane
  if (blk < NG){
    int g = blk;
    uint64_t wv = 0;
    for (int c = 0; c < 4; ++c){
      int i = g*4 + c;
      uint32_t m16 = 0;
      uint32_t d[4] = {0,0,0,0};
      #pragma unroll
      for (int j = 0; j < 16; ++j){
        int k = t*16 + j;
        uint32_t v = (k < NN) ? (uint32_t)(ref[(size_t)i*NN + k] & 1) : 0u;
        m16 |= v << j;
        d[j>>2] |= v << (8*(j&3));
      }
      wv |= (uint64_t)m16 << (16*c);
      refB4[(size_t)i*64 + t] = make_uint4(d[0],d[1],d[2],d[3]);
    }
    pack[(size_t)g*64 + t] = wv;
  } else {
    int b2 = t >> 1;
    int half = t & 1;
    for (int w = half*32; w < half*32 + 32; ++w){
      uint32_t word = 0;
      for (int z = 0; z < 32; ++z){
        int i = w*32 + z;
        if (i < MM){
          float x1 = xoh[(size_t)b2*MM*2 + (size_t)i*2 + 1];
          if (x1 > 0.5f) word |= 1u << z;
        }
      }
      obsw[b2*64 + w] = word;
    }
  }
}

// ---------------- K0b: per-(b2, site) forward scalar table (c0, c1, 1-rn, rn/n) -----
__global__ __launch_bounds__(256) void k_prep2(const float* __restrict__ xoh,
                                               const float* __restrict__ recomb,
                                               float4* __restrict__ FC4){
  int idx = blockIdx.x*256 + threadIdx.x;
  if (idx < NB2*MM){
    int b2 = idx / MM, i = idx - b2*MM;
    float x1 = xoh[(size_t)b2*MM*2 + (size_t)i*2 + 1];
    bool obs = x1 > 0.5f;
    float c0 = obs ? EBV : EAV;
    float c1 = obs ? (EAV-EBV) : (EBV-EAV);
    float rn = (i+1 < MM) ? recomb[i+1] : 0.5f;
    FC4[(size_t)b2*MM + i] = make_float4(c0, c1, 1.0f - rn, rn/(float)NN);
  }
}

// ---------------- K1: GEMM partial ----------------
__global__ __launch_bounds__(256) void k_gemm(const float* __restrict__ gexp,
                                              const float* __restrict__ W,
                                              float* __restrict__ part){
  int cb = blockIdx.x;        // 0..7 column block
  int c  = blockIdx.y;        // 0..15 d-chunk
  int t  = threadIdx.x;
  int d0 = (c*DDIM) >> 4, d1 = ((c+1)*DDIM) >> 4;
  int len = d1 - d0;          // 312 or 313
  __shared__ __align__(16) float lg[313*20];
  for (int bb = 0; bb < 16; ++bb)
    for (int dd = t; dd < len; dd += 256)
      lg[dd*20 + bb] = gexp[(size_t)bb*DDIM + d0 + dd];
  __syncthreads();
  int i = cb*256 + t;
  if (i < MM){
    float acc[16];
    #pragma unroll
    for (int bb = 0; bb < 16; ++bb) acc[bb] = 0.f;
    for (int dd = 0; dd < len; ++dd){
      float w = W[(size_t)(d0 + dd)*MM + i];
      const float4* lp = (const float4*)&lg[dd*20];
      float4 g0 = lp[0], g1 = lp[1], g2 = lp[2], g3 = lp[3];
      acc[0]  += g0.x*w; acc[1]  += g0.y*w; acc[2]  += g0.z*w; acc[3]  += g0.w*w;
      acc[4]  += g1.x*w; acc[5]  += g1.y*w; acc[6]  += g1.z*w; acc[7]  += g1.w*w;
      acc[8]  += g2.x*w; acc[9]  += g2.y*w; acc[10] += g2.z*w; acc[11] += g2.w*w;
      acc[12] += g3.x*w; acc[13] += g3.y*w; acc[14] += g3.z*w; acc[15] += g3.w*w;
    }
    #pragma unroll
    for (int bb = 0; bb < 16; ++bb)
      part[((size_t)c*16 + bb)*MM + i] = acc[bb];
  }
}

// ---------------- K2: reduce partials -> logits; also backward scalar table -----
__global__ __launch_bounds__(256) void k_gemmreduce(const float* __restrict__ part,
                                                    const float* __restrict__ bias,
                                                    const float* __restrict__ recomb,
                                                    float* __restrict__ acc,
                                                    float4* __restrict__ BC4){
  int idx = blockIdx.x*256 + threadIdx.x;
  if (idx < 16*MM){
    float s = 0.f;
    #pragma unroll
    for (int c = 0; c < 16; ++c) s += part[(size_t)c*16*MM + idx];
    acc[idx] = s;
    int bb = idx / MM, i = idx - bb*MM;
    float z = s + bias[i];
    float p = rcp_fast(1.0f + __expf(-z));
    float v0 = EAV + (EBV-EAV)*p;
    float v1 = EBV + (EAV-EBV)*p;
    float r = recomb[i];
    BC4[idx] = make_float4(v0, v1 - v0, 1.0f - r, r/(float)NN);
  }
}

// ---------------- K3: the two sequential chains ------
template<int DIR>
__device__ void run_chain(const uint4* __restrict__ refB4,
                          const float4* __restrict__ ctab,
                          uint16_t* __restrict__ outp,
                          int b2, int lane){
  float t[16];
  #pragma unroll
  for (int j = 0; j < 16; ++j)
    t[j] = (lane*16 + j < NN) ? (1.0f/(float)NN) : 0.0f;
  const bool v62 = lane < 63;   // valid lanes for j in [0,8)
  const bool v61 = lane < 62;   // valid lanes for j in [8,16)
  const bool doSt = lane < 63;  // lane 63 holds only zero pad, never stored

  uint4 Bu[4];                  // rotating ref-byte buffers, 4 sites deep
  float4 CS[4], CN[4];

  auto siteof = [&](int s)->int { return (DIR > 0) ? s : (MM-1 - s); };

  #pragma unroll
  for (int k = 0; k < 4; ++k){
    int st = siteof(k);
    Bu[k] = refB4[(size_t)st*64 + lane];
    CS[k] = ctab[st];
  }

  for (int g = 0; g < NG; ++g){
    #pragma unroll
    for (int k = 0; k < 4; ++k){
      int s = g*4 + k;
      int i = siteof(s);
      float4 sc4 = CS[k];
      // ---- store t (state BEFORE site i) as bf16 ----
      if (doSt){
        uint32_t d[8];
        #pragma unroll
        for (int q = 0; q < 8; ++q){
          uint32_t lo = __float_as_uint(t[2*q])   + 0x8000u;
          uint32_t hi = __float_as_uint(t[2*q+1]) + 0x8000u;
          d[q] = __builtin_amdgcn_perm(hi, lo, 0x07060302u);  // {hi[31:16], lo[31:16]}
        }
        uint4* dp = (uint4*)(outp + ((size_t)i*NB2 + b2)*NPR + lane*16);
        dp[0] = make_uint4(d[0],d[1],d[2],d[3]);
        dp[1] = make_uint4(d[4],d[5],d[6],d[7]);
      }
      // ---- byte ref -> float, w = t * (c0 + c1*b), Z = sum(w) ----
      uint32_t rw[4] = {Bu[k].x, Bu[k].y, Bu[k].z, Bu[k].w};
      float w[16];
      #pragma unroll
      for (int q = 0; q < 4; ++q){
        float b0 = (float)( rw[q]        & 0xFFu);
        float b1 = (float)((rw[q] >> 8)  & 0xFFu);
        float b2f= (float)((rw[q] >> 16) & 0xFFu);
        float b3 = (float)( rw[q] >> 24);
        w[4*q+0] = t[4*q+0] * (sc4.x + sc4.y * b0);
        w[4*q+1] = t[4*q+1] * (sc4.x + sc4.y * b1);
        w[4*q+2] = t[4*q+2] * (sc4.x + sc4.y * b2f);
        w[4*q+3] = t[4*q+3] * (sc4.x + sc4.y * b3);
      }
      float Z = wave_total_sgpr(tree16(w));
      float scf = sc4.z * rcp_fast(Z);
      float adA = v62 ? sc4.w : 0.0f;
      float adB = v61 ? sc4.w : 0.0f;
      #pragma unroll
      for (int j = 0; j < 8; ++j)  t[j] = w[j]*scf + adA;
      #pragma unroll
      for (int j = 8; j < 16; ++j) t[j] = w[j]*scf + adB;
      // ---- prefetch site s+4 into buffer k ----
      if (g+1 < NG){
        int sp = siteof(s+4);
        Bu[k] = refB4[(size_t)sp*64 + lane];
        CN[k] = ctab[sp];
      }
    }
    #pragma unroll
    for (int k = 0; k < 4; ++k) CS[k] = CN[k];
  }
}

__global__ __launch_bounds__(64) void k_chains(const uint4* __restrict__ refB4,
                                               const float4* __restrict__ FC4,
                                               const float4* __restrict__ BC4,
                                               uint16_t* __restrict__ F,
                                               uint16_t* __restrict__ S){
  int lane = threadIdx.x;
  int blk  = blockIdx.x;
  int b2   = blk & 31;
  if (blk < 32) run_chain<1>(refB4, FC4 + (size_t)b2*MM, F, b2, lane);
  else          run_chain<-1>(refB4, BC4 + (size_t)(b2>>1)*MM, S, b2, lane);
}

// ---------------- K4: per-site p_xe terms (fully parallel). wave per (i,b2). ----------
__global__ __launch_bounds__(256) void k_sites(const uint16_t* __restrict__ F,
                                               const uint16_t* __restrict__ S,
                                               const uint64_t* __restrict__ pack,
                                               const uint32_t* __restrict__ obsw,
                                               const float* __restrict__ acc,
                                               const float* __restrict__ bias,
                                               float* __restrict__ terms){
  int lane = threadIdx.x & 63;
  int wid  = threadIdx.x >> 6;
  int s    = blockIdx.x*4 + wid;     // 0 .. 63999
  int i    = s >> 5;
  int b2   = s & 31;
  uint4 f0 = make_uint4(0,0,0,0), f1 = f0, s0 = f0, s1 = f0;
  if (lane < 63){
    size_t off = ((size_t)i*NB2 + b2)*NPR + lane*16;
    const uint4* fp = (const uint4*)(F + off);
    const uint4* sp = (const uint4*)(S + off);
    f0 = fp[0]; f1 = fp[1];
    s0 = sp[0]; s1 = sp[1];
  }
  uint32_t m16 = (uint32_t)(pack[(size_t)(i>>2)*64 + lane] >> (16*(i&3))) & 0xFFFFu;

  uint32_t fa[8] = {f0.x,f0.y,f0.z,f0.w,f1.x,f1.y,f1.z,f1.w};
  uint32_t sa[8] = {s0.x,s0.y,s0.z,s0.w,s1.x,s1.y,s1.z,s1.w};
  float Tt = 0.f, Tb = 0.f;
  #pragma unroll
  for (int q = 0; q < 8; ++q){
    float flo = __uint_as_float(fa[q] << 16);
    float fhi = __uint_as_float(fa[q] & 0xFFFF0000u);
    float slo = __uint_as_float(sa[q] << 16);
    float shi = __uint_as_float(sa[q] & 0xFFFF0000u);
    float pl = flo*slo, ph = fhi*shi;
    Tt += pl + ph;
    Tb += (((m16 >> (2*q)) & 1u) ? pl : 0.f) + (((m16 >> (2*q+1)) & 1u) ? ph : 0.f);
  }
  Tt = wave_allsum(Tt);
  Tb = wave_allsum(Tb);
  if (lane == 0){
    uint32_t obsb = (obsw[b2*64 + (i>>5)] >> (i & 31)) & 1u;
    float z = acc[(size_t)(b2 >> 1)*MM + i] + bias[i];
    float p = rcp_fast(1.0f + __expf(-z));
    float A = Tt - Tb, B = Tb;
    float d0 = EAV*A + EBV*B;
    float d1 = EBV*A + EAV*B;
    float w0 = d0*(1.0f - p), w1 = d1*p;
    float term = __logf((obsb ? w1 : w0) * rcp_fast(w0 + w1));
    terms[s] = term;
  }
}

// ---------------- K5: final reduction ----------
__global__ __launch_bounds__(256) void k_final(const float* __restrict__ terms,
                                               float* __restrict__ out){
  __shared__ float red[256];
  float s = 0.f;
  for (int idx = threadIdx.x; idx < MM*NB2; idx += 256) s += terms[idx];
  red[threadIdx.x] = s;
  __syncthreads();
  for (int st = 128; st > 0; st >>= 1){
    if (threadIdx.x < st) red[threadIdx.x] += red[threadIdx.x + st];
    __syncthreads();
  }
  if (threadIdx.x == 0) out[0] = -red[0];
}

extern "C" void kernel_launch(void* const* d_in, const int* in_sizes, int n_in,
                              void* d_out, int out_size, void* d_ws, size_t ws_size,
                              hipStream_t stream){
  const float* gexp   = (const float*)d_in[0];   // [16,5000]
  const float* xoh    = (const float*)d_in[1];   // [32,2000,2]
  const float* W      = (const float*)d_in[2];   // [5000,2000]
  const float* bias   = (const float*)d_in[3];   // [2000]
  const int*   ref    = (const int*)d_in[4];     // [2000,1000]
  const float* recomb = (const float*)d_in[5];   // [2000]
  float* out = (float*)d_out;
  char* ws = (char*)d_ws;

  // Total footprint 264,328,192 B — below Round-1 proven 264,840,192 B.
  const size_t stateBytes = (size_t)MM*NB2*NPR*2;      // 129,024,000 per array (bf16)
  size_t offF    = 0;
  size_t offS    = offF + stateBytes;                  // 129,024,000
  size_t offPack = offS + stateBytes;                  // 258,048,000
  size_t offObs  = offPack + (size_t)NG*64*8;          // 258,304,000
  size_t offPart = offObs + 32*64*4;                   // 258,312,192
  size_t offAcc  = offPart + (size_t)16*16*MM*4;       // 260,360,192
  size_t offTerm = offAcc + (size_t)16*MM*4;           // 260,488,192
  size_t offRefB = offTerm + (size_t)MM*NB2*4;         // 260,744,192
  size_t offFC4  = offRefB + (size_t)MM*1024;          // 262,792,192
  size_t offBC4  = offFC4 + (size_t)NB2*MM*16;         // 263,816,192 (+512,000 = 264,328,192)

  uint16_t* Fb   = (uint16_t*)(ws + offF);
  uint16_t* Sb   = (uint16_t*)(ws + offS);
  uint64_t* pack = (uint64_t*)(ws + offPack);
  uint32_t* obsw = (uint32_t*)(ws + offObs);
  float*    part = (float*)(ws + offPart);
  float*    accp = (float*)(ws + offAcc);
  float*    term = (float*)(ws + offTerm);
  uint4*    refB = (uint4*)(ws + offRefB);
  float4*   FC4  = (float4*)(ws + offFC4);
  float4*   BC4  = (float4*)(ws + offBC4);

  hipLaunchKernelGGL(k_pack, dim3(NG+1), dim3(64), 0, stream, ref, xoh, pack, refB, obsw);
  hipLaunchKernelGGL(k_prep2, dim3((NB2*MM+255)/256), dim3(256), 0, stream, xoh, recomb, FC4);
  hipLaunchKernelGGL(k_gemm, dim3(8,16), dim3(256), 0, stream, gexp, W, part);
  hipLaunchKernelGGL(k_gemmreduce, dim3(125), dim3(256), 0, stream, part, bias, recomb, accp, BC4);
  hipLaunchKernelGGL(k_chains, dim3(64), dim3(64), 0, stream, refB, FC4, BC4, Fb, Sb);
  hipLaunchKernelGGL(k_sites, dim3(MM*NB2/4), dim3(256), 0, stream, Fb, Sb, pack, obsw, accp, bias, term);
  hipLaunchKernelGGL(k_final, dim3(1), dim3(256), 0, stream, term, out);
}

// Round 5
// 919.884 us; speedup vs baseline: 1.5462x; 1.2146x over previous
//
#include <hip/hip_runtime.h>
#include <stdint.h>
#include <stddef.h>

static constexpr int MM   = 2000;   // sites
static constexpr int NN   = 1000;   // states
static constexpr int NB2  = 32;     // 2B haplotype rows
static constexpr int DDIM = 5000;   // gexp dim
static constexpr int NPR  = 1008;   // F/S row stride in elements (63 lanes x 16)
static constexpr int NG   = 500;    // MM/4 groups
static constexpr float EAV = 0.991f; // (1-0.01) + 1/1000
static constexpr float EBV = 0.011f; // 0.01 + 1/1000

typedef uint32_t u32x4 __attribute__((ext_vector_type(4)));

__device__ __forceinline__ float rcp_fast(float x){ return __builtin_amdgcn_rcpf(x); }

__device__ __forceinline__ float tree16(const float* w){
  float a = ((w[0]+w[1]) + (w[2]+w[3])) + ((w[4]+w[5]) + (w[6]+w[7]));
  float b = ((w[8]+w[9]) + (w[10]+w[11])) + ((w[12]+w[13]) + (w[14]+w[15]));
  return a + b;
}

// Full-wave sum via DPP; result read from lane 63 into an SGPR (uniform).
// Verified on HW in Round 3 (absmax 0.0).
__device__ __forceinline__ float wave_total_sgpr(float v){
  int x;
  x = __builtin_amdgcn_update_dpp(0, __float_as_int(v), 0x111, 0xf, 0xf, true);  v += __int_as_float(x); // row_shr:1
  x = __builtin_amdgcn_update_dpp(0, __float_as_int(v), 0x112, 0xf, 0xf, true);  v += __int_as_float(x); // row_shr:2
  x = __builtin_amdgcn_update_dpp(0, __float_as_int(v), 0x114, 0xf, 0xf, true);  v += __int_as_float(x); // row_shr:4
  x = __builtin_amdgcn_update_dpp(0, __float_as_int(v), 0x118, 0xf, 0xf, true);  v += __int_as_float(x); // row_shr:8
  x = __builtin_amdgcn_update_dpp(0, __float_as_int(v), 0x142, 0xa, 0xf, false); v += __int_as_float(x); // row_bcast:15
  x = __builtin_amdgcn_update_dpp(0, __float_as_int(v), 0x143, 0xc, 0xf, false); v += __int_as_float(x); // row_bcast:31
  return __int_as_float(__builtin_amdgcn_readlane(__float_as_int(v), 63));
}

// ---------------- K0: pack ref bits + ref bytes + obs bits -----
__global__ __launch_bounds__(64) void k_pack(const int* __restrict__ ref,
                                             const float* __restrict__ xoh,
                                             uint64_t* __restrict__ pack,
                                             uint4* __restrict__ refB4,
                                             uint32_t* __restrict__ obsw){
  int blk = blockIdx.x;
  int t = threadIdx.x;   // lane
  if (blk < NG){
    int g = blk;
    uint64_t wv = 0;
    for (int c = 0; c < 4; ++c){
      int i = g*4 + c;
      uint32_t m16 = 0;
      uint32_t d[4] = {0,0,0,0};
      #pragma unroll
      for (int j = 0; j < 16; ++j){
        int k = t*16 + j;
        uint32_t v = (k < NN) ? (uint32_t)(ref[(size_t)i*NN + k] & 1) : 0u;
        m16 |= v << j;
        d[j>>2] |= v << (8*(j&3));
      }
      wv |= (uint64_t)m16 << (16*c);
      refB4[(size_t)i*64 + t] = make_uint4(d[0],d[1],d[2],d[3]);
    }
    pack[(size_t)g*64 + t] = wv;
  } else {
    int b2 = t >> 1;
    int half = t & 1;
    for (int w = half*32; w < half*32 + 32; ++w){
      uint32_t word = 0;
      for (int z = 0; z < 32; ++z){
        int i = w*32 + z;
        if (i < MM){
          float x1 = xoh[(size_t)b2*MM*2 + (size_t)i*2 + 1];
          if (x1 > 0.5f) word |= 1u << z;
        }
      }
      obsw[b2*64 + w] = word;
    }
  }
}

// ---------------- K0b: per-(b2, site) forward scalar table (c0, c1, 1-rn, rn/n) -----
__global__ __launch_bounds__(256) void k_prep2(const float* __restrict__ xoh,
                                               const float* __restrict__ recomb,
                                               float4* __restrict__ FC4){
  int idx = blockIdx.x*256 + threadIdx.x;
  if (idx < NB2*MM){
    int b2 = idx / MM, i = idx - b2*MM;
    float x1 = xoh[(size_t)b2*MM*2 + (size_t)i*2 + 1];
    bool obs = x1 > 0.5f;
    float c0 = obs ? EBV : EAV;
    float c1 = obs ? (EAV-EBV) : (EBV-EAV);
    float rn = (i+1 < MM) ? recomb[i+1] : 0.5f;
    FC4[(size_t)b2*MM + i] = make_float4(c0, c1, 1.0f - rn, rn/(float)NN);
  }
}

// ---------------- K1: GEMM partial ----------------
__global__ __launch_bounds__(256) void k_gemm(const float* __restrict__ gexp,
                                              const float* __restrict__ W,
                                              float* __restrict__ part){
  int cb = blockIdx.x;        // 0..7 column block
  int c  = blockIdx.y;        // 0..15 d-chunk
  int t  = threadIdx.x;
  int d0 = (c*DDIM) >> 4, d1 = ((c+1)*DDIM) >> 4;
  int len = d1 - d0;          // 312 or 313
  __shared__ __align__(16) float lg[313*20];
  for (int bb = 0; bb < 16; ++bb)
    for (int dd = t; dd < len; dd += 256)
      lg[dd*20 + bb] = gexp[(size_t)bb*DDIM + d0 + dd];
  __syncthreads();
  int i = cb*256 + t;
  if (i < MM){
    float acc[16];
    #pragma unroll
    for (int bb = 0; bb < 16; ++bb) acc[bb] = 0.f;
    for (int dd = 0; dd < len; ++dd){
      float w = W[(size_t)(d0 + dd)*MM + i];
      const float4* lp = (const float4*)&lg[dd*20];
      float4 g0 = lp[0], g1 = lp[1], g2 = lp[2], g3 = lp[3];
      acc[0]  += g0.x*w; acc[1]  += g0.y*w; acc[2]  += g0.z*w; acc[3]  += g0.w*w;
      acc[4]  += g1.x*w; acc[5]  += g1.y*w; acc[6]  += g1.z*w; acc[7]  += g1.w*w;
      acc[8]  += g2.x*w; acc[9]  += g2.y*w; acc[10] += g2.z*w; acc[11] += g2.w*w;
      acc[12] += g3.x*w; acc[13] += g3.y*w; acc[14] += g3.z*w; acc[15] += g3.w*w;
    }
    #pragma unroll
    for (int bb = 0; bb < 16; ++bb)
      part[((size_t)c*16 + bb)*MM + i] = acc[bb];
  }
}

// ---------------- K2: reduce partials -> logits; also backward scalar table -----
__global__ __launch_bounds__(256) void k_gemmreduce(const float* __restrict__ part,
                                                    const float* __restrict__ bias,
                                                    const float* __restrict__ recomb,
                                                    float* __restrict__ acc,
                                                    float4* __restrict__ BC4){
  int idx = blockIdx.x*256 + threadIdx.x;
  if (idx < 16*MM){
    float s = 0.f;
    #pragma unroll
    for (int c = 0; c < 16; ++c) s += part[(size_t)c*16*MM + idx];
    acc[idx] = s;
    int bb = idx / MM, i = idx - bb*MM;
    float z = s + bias[i];
    float p = rcp_fast(1.0f + __expf(-z));
    float v0 = EAV + (EBV-EAV)*p;
    float v1 = EBV + (EAV-EBV)*p;
    float r = recomb[i];
    BC4[idx] = make_float4(v0, v1 - v0, 1.0f - r, r/(float)NN);
  }
}

// ---------------- K3: the two sequential chains ------
// refB4 points at site 0; allocation has >=16 sites of pad on BOTH sides so
// prefetch loads are unconditional. ctab cached in LDS (uniform ds_read).
template<int DIR>
__device__ void run_chain(const uint4* __restrict__ refB4,
                          const float4* __restrict__ ctab,
                          uint16_t* __restrict__ outp,
                          int b2, int lane){
  __shared__ __align__(16) float4 lds_ctab[MM];
  for (int idx = lane; idx < MM; idx += 64) lds_ctab[idx] = ctab[idx];
  __syncthreads();

  float t[16];
  #pragma unroll
  for (int j = 0; j < 16; ++j) t[j] = (lane*16 + j < NN) ? (1.0f/(float)NN) : 0.0f;
  const float mA = (lane < 63) ? 1.0f : 0.0f;   // states 1000..1023 stay exactly 0
  const float mB = (lane < 62) ? 1.0f : 0.0f;
  const bool doSt = lane < 63;                  // lane 63 is all-pad, never stored

  const ptrdiff_t rstep = (ptrdiff_t)DIR * 64;  // uint4 units per site
  const uint4* rp = refB4 + ((DIR > 0) ? 0 : (ptrdiff_t)(MM-1)*64) + lane;
  const ptrdiff_t ostep = (ptrdiff_t)DIR * NB2 * NPR;  // uint16 units per site
  uint16_t* op = outp + (size_t)b2*NPR
               + ((DIR > 0) ? (size_t)0 : (size_t)(MM-1)*(size_t)NB2*NPR)
               + (size_t)lane*16;

  uint4 A[8], Bv[8];
  #pragma unroll
  for (int k = 0; k < 8; ++k) A[k]  = rp[(ptrdiff_t)k*rstep];
  #pragma unroll
  for (int k = 0; k < 8; ++k) Bv[k] = rp[(ptrdiff_t)(k+8)*rstep];

  int ci = (DIR > 0) ? 0 : (MM-1);   // ctab index of current site

  #pragma unroll 2
  for (int n = 0; n < MM/8; ++n){
    uint4 Cv[8];
    #pragma unroll
    for (int k = 0; k < 8; ++k) Cv[k] = rp[(ptrdiff_t)(8*n + 16 + k)*rstep];
    #pragma unroll
    for (int k = 0; k < 8; ++k){
      float4 sc4 = lds_ctab[ci];
      // ---- store t (state BEFORE this site) as bf16, nontemporal ----
      if (doSt){
        uint32_t d[8];
        #pragma unroll
        for (int q = 0; q < 8; ++q){
          uint32_t lo = __float_as_uint(t[2*q])   + 0x8000u;
          uint32_t hi = __float_as_uint(t[2*q+1]) + 0x8000u;
          d[q] = __builtin_amdgcn_perm(hi, lo, 0x07060302u);  // {hi[31:16], lo[31:16]}
        }
        u32x4* dp = (u32x4*)op;
        u32x4 v0; v0.x = d[0]; v0.y = d[1]; v0.z = d[2]; v0.w = d[3];
        u32x4 v1; v1.x = d[4]; v1.y = d[5]; v1.z = d[6]; v1.w = d[7];
        __builtin_nontemporal_store(v0, dp);
        __builtin_nontemporal_store(v1, dp + 1);
      }
      op += ostep;
      // ---- byte ref -> float, w = t * (c0 + c1*b), Z = sum(w) ----
      uint32_t rw[4] = {A[k].x, A[k].y, A[k].z, A[k].w};
      float w[16];
      #pragma unroll
      for (int q = 0; q < 4; ++q){
        float b0 = (float)( rw[q]        & 0xFFu);
        float b1 = (float)((rw[q] >> 8)  & 0xFFu);
        float b2f= (float)((rw[q] >> 16) & 0xFFu);
        float b3 = (float)( rw[q] >> 24);
        w[4*q+0] = t[4*q+0] * (sc4.x + sc4.y * b0);
        w[4*q+1] = t[4*q+1] * (sc4.x + sc4.y * b1);
        w[4*q+2] = t[4*q+2] * (sc4.x + sc4.y * b2f);
        w[4*q+3] = t[4*q+3] * (sc4.x + sc4.y * b3);
      }
      float Z = wave_total_sgpr(tree16(w));
      float scf = sc4.z * rcp_fast(Z);
      float adA = sc4.w * mA;
      float adB = sc4.w * mB;
      #pragma unroll
      for (int j = 0; j < 8; ++j)  t[j] = w[j]*scf + adA;
      #pragma unroll
      for (int j = 8; j < 16; ++j) t[j] = w[j]*scf + adB;
      ci += DIR;
    }
    #pragma unroll
    for (int k = 0; k < 8; ++k){ A[k] = Bv[k]; Bv[k] = Cv[k]; }
  }
}

__global__ __launch_bounds__(64, 1) void k_chains(const uint4* __restrict__ refB4,
                                                  const float4* __restrict__ FC4,
                                                  const float4* __restrict__ BC4,
                                                  uint16_t* __restrict__ F,
                                                  uint16_t* __restrict__ S){
  int lane = threadIdx.x;
  int blk  = blockIdx.x;
  int b2   = blk & 31;
  if (blk < 32) run_chain<1>(refB4, FC4 + (size_t)b2*MM, F, b2, lane);
  else          run_chain<-1>(refB4, BC4 + (size_t)(b2>>1)*MM, S, b2, lane);
}

// ---------------- K4: per-site p_xe terms (fully parallel). wave per (i,b2). ----------
__global__ __launch_bounds__(256) void k_sites(const uint16_t* __restrict__ F,
                                               const uint16_t* __restrict__ S,
                                               const uint64_t* __restrict__ pack,
                                               const uint32_t* __restrict__ obsw,
                                               const float* __restrict__ acc,
                                               const float* __restrict__ bias,
                                               float* __restrict__ terms){
  int lane = threadIdx.x & 63;
  int wid  = threadIdx.x >> 6;
  int s    = blockIdx.x*4 + wid;     // 0 .. 63999
  int i    = s >> 5;
  int b2   = s & 31;
  uint4 f0 = make_uint4(0,0,0,0), f1 = f0, s0 = f0, s1 = f0;
  if (lane < 63){
    size_t off = ((size_t)i*NB2 + b2)*NPR + lane*16;
    const uint4* fp = (const uint4*)(F + off);
    const uint4* sp = (const uint4*)(S + off);
    f0 = fp[0]; f1 = fp[1];
    s0 = sp[0]; s1 = sp[1];
  }
  uint32_t m16 = (uint32_t)(pack[(size_t)(i>>2)*64 + lane] >> (16*(i&3))) & 0xFFFFu;

  uint32_t fa[8] = {f0.x,f0.y,f0.z,f0.w,f1.x,f1.y,f1.z,f1.w};
  uint32_t sa[8] = {s0.x,s0.y,s0.z,s0.w,s1.x,s1.y,s1.z,s1.w};
  float Tt = 0.f, Tb = 0.f;
  #pragma unroll
  for (int q = 0; q < 8; ++q){
    float flo = __uint_as_float(fa[q] << 16);
    float fhi = __uint_as_float(fa[q] & 0xFFFF0000u);
    float slo = __uint_as_float(sa[q] << 16);
    float shi = __uint_as_float(sa[q] & 0xFFFF0000u);
    float pl = flo*slo, ph = fhi*shi;
    Tt += pl + ph;
    Tb += (((m16 >> (2*q)) & 1u) ? pl : 0.f) + (((m16 >> (2*q+1)) & 1u) ? ph : 0.f);
  }
  Tt = wave_total_sgpr(Tt);
  Tb = wave_total_sgpr(Tb);
  if (lane == 0){
    uint32_t obsb = (obsw[b2*64 + (i>>5)] >> (i & 31)) & 1u;
    float z = acc[(size_t)(b2 >> 1)*MM + i] + bias[i];
    float p = rcp_fast(1.0f + __expf(-z));
    float A = Tt - Tb, B = Tb;
    float d0 = EAV*A + EBV*B;
    float d1 = EBV*A + EAV*B;
    float w0 = d0*(1.0f - p), w1 = d1*p;
    float term = __logf((obsb ? w1 : w0) * rcp_fast(w0 + w1));
    terms[s] = term;
  }
}

// ---------------- K5: final reduction ----------
__global__ __launch_bounds__(256) void k_final(const float* __restrict__ terms,
                                               float* __restrict__ out){
  __shared__ float red[256];
  float s = 0.f;
  for (int idx = threadIdx.x; idx < MM*NB2; idx += 256) s += terms[idx];
  red[threadIdx.x] = s;
  __syncthreads();
  for (int st = 128; st > 0; st >>= 1){
    if (threadIdx.x < st) red[threadIdx.x] += red[threadIdx.x + st];
    __syncthreads();
  }
  if (threadIdx.x == 0) out[0] = -red[0];
}

extern "C" void kernel_launch(void* const* d_in, const int* in_sizes, int n_in,
                              void* d_out, int out_size, void* d_ws, size_t ws_size,
                              hipStream_t stream){
  const float* gexp   = (const float*)d_in[0];   // [16,5000]
  const float* xoh    = (const float*)d_in[1];   // [32,2000,2]
  const float* W      = (const float*)d_in[2];   // [5000,2000]
  const float* bias   = (const float*)d_in[3];   // [2000]
  const int*   ref    = (const int*)d_in[4];     // [2000,1000]
  const float* recomb = (const float*)d_in[5];   // [2000]
  float* out = (float*)d_out;
  char* ws = (char*)d_ws;

  // Total footprint 264,360,960 B — below Round-1 proven 264,840,192 B.
  const size_t stateBytes = (size_t)MM*NB2*NPR*2;      // 129,024,000 per array (bf16)
  size_t offF    = 0;
  size_t offS    = offF + stateBytes;                  // 129,024,000
  size_t offPack = offS + stateBytes;                  // 258,048,000
  size_t offObs  = offPack + (size_t)NG*64*8;          // 258,304,000
  size_t offPart = offObs + 32*64*4;                   // 258,312,192
  size_t offAcc  = offPart + (size_t)16*16*MM*4;       // 260,360,192
  size_t offTerm = offAcc + (size_t)16*MM*4;           // 260,488,192
  size_t offRefB = offTerm + (size_t)MM*NB2*4;         // 260,744,192
  // refB region: (MM+32) sites x 1 KB, usable base at +16 sites
  size_t offFC4  = offRefB + (size_t)(MM+32)*1024;     // 262,824,960
  size_t offBC4  = offFC4 + (size_t)NB2*MM*16;         // 263,848,960 (+512,000 = 264,360,960)

  uint16_t* Fb   = (uint16_t*)(ws + offF);
  uint16_t* Sb   = (uint16_t*)(ws + offS);
  uint64_t* pack = (uint64_t*)(ws + offPack);
  uint32_t* obsw = (uint32_t*)(ws + offObs);
  float*    part = (float*)(ws + offPart);
  float*    accp = (float*)(ws + offAcc);
  float*    term = (float*)(ws + offTerm);
  uint4*    refB = (uint4*)(ws + offRefB) + 16*64;     // site 0, pad +/-16 sites
  float4*   FC4  = (float4*)(ws + offFC4);
  float4*   BC4  = (float4*)(ws + offBC4);

  hipLaunchKernelGGL(k_pack, dim3(NG+1), dim3(64), 0, stream, ref, xoh, pack, refB, obsw);
  hipLaunchKernelGGL(k_prep2, dim3((NB2*MM+255)/256), dim3(256), 0, stream, xoh, recomb, FC4);
  hipLaunchKernelGGL(k_gemm, dim3(8,16), dim3(256), 0, stream, gexp, W, part);
  hipLaunchKernelGGL(k_gemmreduce, dim3(125), dim3(256), 0, stream, part, bias, recomb, accp, BC4);
  hipLaunchKernelGGL(k_chains, dim3(64), dim3(64), 0, stream, refB, FC4, BC4, Fb, Sb);
  hipLaunchKernelGGL(k_sites, dim3(MM*NB2/4), dim3(256), 0, stream, Fb, Sb, pack, obsw, accp, bias, term);
  hipLaunchKernelGGL(k_final, dim3(1), dim3(256), 0, stream, term, out);
}